// Round 1
// baseline (785.639 us; speedup 1.0000x reference)
//
#include <hip/hip_runtime.h>
#include <hip/hip_bf16.h>
#include <cstdint>

#define S_LEN 2048
#define DMODEL 4096
#define NHEAD 32
#define NKV 8
#define HDIM 128
#define MAXSEQ 4096
#define NQKV 6144   // 4096 + 1024 + 1024

typedef __bf16 bf16x8 __attribute__((ext_vector_type(8)));
typedef float f32x4 __attribute__((ext_vector_type(4)));
typedef short s16x4 __attribute__((ext_vector_type(4)));

__device__ __forceinline__ short f2bf(float f) {
  unsigned u = __builtin_bit_cast(unsigned, f);
  u += 0x7fffu + ((u >> 16) & 1u);
  return (short)(u >> 16);
}

__device__ __forceinline__ void gload_lds16(const void* g, const void* l) {
  __builtin_amdgcn_global_load_lds((const __attribute__((address_space(1))) unsigned*)g,
                                   (__attribute__((address_space(3))) unsigned*)(l), 16, 0, 0);
}

// ---------------- RMSNorm: fp32 in -> bf16 out ----------------
__global__ __launch_bounds__(256) void rmsnorm_kernel(const float* __restrict__ x,
                                                      const float* __restrict__ w,
                                                      short* __restrict__ out) {
  const int row = blockIdx.x, tid = threadIdx.x;
  const float4* xr = (const float4*)(x + (size_t)row * DMODEL);
  const float4* wr = (const float4*)w;
  float4 v[4];
  float ss = 0.f;
#pragma unroll
  for (int i = 0; i < 4; ++i) {
    v[i] = xr[tid + i * 256];
    ss += v[i].x * v[i].x + v[i].y * v[i].y + v[i].z * v[i].z + v[i].w * v[i].w;
  }
#pragma unroll
  for (int m = 32; m; m >>= 1) ss += __shfl_down(ss, m, 64);
  __shared__ float red[4];
  if ((tid & 63) == 0) red[tid >> 6] = ss;
  __syncthreads();
  float tot = red[0] + red[1] + red[2] + red[3];
  float sc = rsqrtf(tot * (1.f / DMODEL) + 1e-5f);
#pragma unroll
  for (int i = 0; i < 4; ++i) {
    float4 wv = wr[tid + i * 256];
    s16x4 o;
    o[0] = f2bf(v[i].x * sc * wv.x);
    o[1] = f2bf(v[i].y * sc * wv.y);
    o[2] = f2bf(v[i].z * sc * wv.z);
    o[3] = f2bf(v[i].w * sc * wv.w);
    *(s16x4*)&out[(size_t)row * DMODEL + (size_t)(tid + i * 256) * 4] = o;
  }
}

// ---------------- cast fp32 (rows x cols) -> bf16 transposed (cols x rows) ----------------
// dst[c * rows + r] = src[r * cols + c]
__global__ __launch_bounds__(256) void cast_transpose(const float* __restrict__ src,
                                                      short* __restrict__ dst,
                                                      int rows, int cols) {
  __shared__ float tile[32][33];
  const int c0 = blockIdx.x * 32, r0 = blockIdx.y * 32;
  const int tx = threadIdx.x, ty = threadIdx.y;
#pragma unroll
  for (int i = ty; i < 32; i += 8) tile[i][tx] = src[(size_t)(r0 + i) * cols + c0 + tx];
  __syncthreads();
#pragma unroll
  for (int i = ty; i < 32; i += 8)
    dst[(size_t)(c0 + i) * rows + r0 + tx] = f2bf(tile[tx][i]);
}

// ---------------- bf16 MFMA GEMM: C(MxN fp32) = A(MxK) * Bt(NxK)^T  (+ optional residual) ----------------
__global__ __launch_bounds__(256, 2) void gemm_bt(const short* __restrict__ A,
                                                  const short* __restrict__ Bt,
                                                  float* __restrict__ C,
                                                  const float* __restrict__ resid,
                                                  int M, int N, int K) {
  __shared__ __align__(16) short As[128 * 64];
  __shared__ __align__(16) short Bs[128 * 64];
  const int tid = threadIdx.x;
  const int lane = tid & 63, wave = tid >> 6;
  const int wr = wave >> 1, wc = wave & 1;
  const int lrow = lane & 15, quad = lane >> 4;
  const int m0 = blockIdx.y * 128, n0 = blockIdx.x * 128;
  f32x4 acc[4][4] = {};
  for (int k0 = 0; k0 < K; k0 += 64) {
#pragma unroll
    for (int c = 0; c < 4; ++c) {
      int idx = (wave * 4 + c) * 512 + lane * 8;
      int row = idx >> 6, kc = idx & 63;
      gload_lds16(A + (size_t)(m0 + row) * K + k0 + kc, &As[(wave * 4 + c) * 512]);
      gload_lds16(Bt + (size_t)(n0 + row) * K + k0 + kc, &Bs[(wave * 4 + c) * 512]);
    }
    __syncthreads();
#pragma unroll
    for (int kk = 0; kk < 2; ++kk) {
      bf16x8 af[4], bfr[4];
#pragma unroll
      for (int i = 0; i < 4; ++i)
        af[i] = *(const bf16x8*)&As[(wr * 64 + i * 16 + lrow) * 64 + kk * 32 + quad * 8];
#pragma unroll
      for (int j = 0; j < 4; ++j)
        bfr[j] = *(const bf16x8*)&Bs[(wc * 64 + j * 16 + lrow) * 64 + kk * 32 + quad * 8];
#pragma unroll
      for (int i = 0; i < 4; ++i)
#pragma unroll
        for (int j = 0; j < 4; ++j)
          acc[i][j] = __builtin_amdgcn_mfma_f32_16x16x32_bf16(af[i], bfr[j], acc[i][j], 0, 0, 0);
    }
    __syncthreads();
  }
#pragma unroll
  for (int i = 0; i < 4; ++i)
#pragma unroll
    for (int j = 0; j < 4; ++j) {
      int row = m0 + wr * 64 + i * 16 + quad * 4;
      int col = n0 + wc * 64 + j * 16 + lrow;
#pragma unroll
      for (int r = 0; r < 4; ++r) {
        float v = acc[i][j][r];
        size_t o = (size_t)(row + r) * N + col;
        if (resid) v += resid[o];
        C[o] = v;
      }
    }
}

// ---------------- RoPE (interleaved) + cache write + attention-layout staging ----------------
__global__ __launch_bounds__(256) void rope_kernel(const float* __restrict__ QKV,
                                                   const float* __restrict__ cosb,
                                                   const float* __restrict__ sinb,
                                                   short* __restrict__ qo,
                                                   short* __restrict__ ko,
                                                   short* __restrict__ vt,
                                                   float* __restrict__ kc,
                                                   float* __restrict__ vc) {
  const int s = blockIdx.x, tid = threadIdx.x;
  const float* row = QKV + (size_t)s * NQKV;
  const float* cr = cosb + (size_t)s * HDIM;
  const float* sr = sinb + (size_t)s * HDIM;
  const float qscale = 0.08838834764831845f;  // 1/sqrt(128) folded into Q
  // Q: 32 heads * 64 pairs
  for (int p = tid; p < NHEAD * 64; p += 256) {
    int hh = p >> 6, d = (p & 63) * 2;
    float x0 = row[hh * HDIM + d], x1 = row[hh * HDIM + d + 1];
    float c = cr[d], si = sr[d];
    float o0 = (x0 * c - x1 * si) * qscale;
    float o1 = (x1 * c + x0 * si) * qscale;
    size_t o = ((size_t)hh * S_LEN + s) * HDIM + d;
    qo[o] = f2bf(o0);
    qo[o + 1] = f2bf(o1);
  }
  // K: 8 kv-heads * 64 pairs
  for (int p = tid; p < NKV * 64; p += 256) {
    int g = p >> 6, d = (p & 63) * 2;
    float x0 = row[NHEAD * HDIM + g * HDIM + d], x1 = row[NHEAD * HDIM + g * HDIM + d + 1];
    float c = cr[d], si = sr[d];
    float o0 = x0 * c - x1 * si;
    float o1 = x1 * c + x0 * si;
    size_t o = ((size_t)g * S_LEN + s) * HDIM + d;
    ko[o] = f2bf(o0);
    ko[o + 1] = f2bf(o1);
    kc[(size_t)s * (NKV * HDIM) + g * HDIM + d] = o0;
    kc[(size_t)s * (NKV * HDIM) + g * HDIM + d + 1] = o1;
  }
  // V: 1024 elements -> fp32 cache + bf16 transposed [g][d][s]
  for (int e = tid; e < NKV * HDIM; e += 256) {
    int g = e >> 7, d = e & 127;
    float v = row[(NHEAD + NKV) * HDIM + e];
    vc[(size_t)s * (NKV * HDIM) + e] = v;
    vt[((size_t)g * HDIM + d) * S_LEN + s] = f2bf(v);
  }
}

// ---------------- zero cache tail rows [S_LEN, MAXSEQ) ----------------
__global__ __launch_bounds__(256) void zero_tail(float* __restrict__ kc, float* __restrict__ vc) {
  size_t i = (size_t)blockIdx.x * 256 + threadIdx.x;
  const size_t tail4 = (size_t)(MAXSEQ - S_LEN) * NKV * HDIM / 4;  // 524288
  float4 z = make_float4(0.f, 0.f, 0.f, 0.f);
  float4* kt = (float4*)(kc + (size_t)S_LEN * NKV * HDIM);
  float4* vt = (float4*)(vc + (size_t)S_LEN * NKV * HDIM);
  if (i < tail4) kt[i] = z;
  else if (i < 2 * tail4) vt[i - tail4] = z;
}

// ---------------- GQA causal flash attention ----------------
// grid: (S/32, NKV); block 256 = 4 waves, wave w -> head g*4+w, 32 q-rows
__global__ __launch_bounds__(256, 2) void attn_kernel(const short* __restrict__ Q,
                                                      const short* __restrict__ Kb,
                                                      const short* __restrict__ Vt,
                                                      short* __restrict__ out) {
  __shared__ __align__(16) short Ks[32 * 128];
  __shared__ __align__(16) short Vs[128 * 32];
  __shared__ __align__(16) short Ps[4][32 * 32];
  const int tid = threadIdx.x;
  const int lane = tid & 63, wave = tid >> 6;
  const int lrow = lane & 15, quad = lane >> 4;
  const int qb = blockIdx.x, g = blockIdx.y;
  const int h = g * 4 + wave;
  const float L2E = 1.44269504f;

  bf16x8 qf[2][4];
#pragma unroll
  for (int i = 0; i < 2; ++i)
#pragma unroll
    for (int kf = 0; kf < 4; ++kf)
      qf[i][kf] = *(const bf16x8*)&Q[((size_t)h * S_LEN + qb * 32 + i * 16 + lrow) * HDIM + kf * 32 + quad * 8];

  f32x4 O[2][8] = {};
  float mrun[2][4], lrun[2][4];
#pragma unroll
  for (int i = 0; i < 2; ++i)
#pragma unroll
    for (int r = 0; r < 4; ++r) { mrun[i][r] = -INFINITY; lrun[i][r] = 0.f; }

  for (int kt = 0; kt <= qb; ++kt) {
#pragma unroll
    for (int c = 0; c < 2; ++c) {
      int idx = (wave * 2 + c) * 512 + lane * 8;
      gload_lds16(Kb + ((size_t)g * S_LEN + kt * 32 + (idx >> 7)) * HDIM + (idx & 127),
                  &Ks[(wave * 2 + c) * 512]);
      gload_lds16(Vt + ((size_t)g * HDIM + (idx >> 5)) * S_LEN + kt * 32 + (idx & 31),
                  &Vs[(wave * 2 + c) * 512]);
    }
    __syncthreads();

    f32x4 sacc[2][2] = {};
#pragma unroll
    for (int kf = 0; kf < 4; ++kf) {
      bf16x8 k0 = *(const bf16x8*)&Ks[lrow * 128 + kf * 32 + quad * 8];
      bf16x8 k1 = *(const bf16x8*)&Ks[(16 + lrow) * 128 + kf * 32 + quad * 8];
#pragma unroll
      for (int i = 0; i < 2; ++i) {
        sacc[i][0] = __builtin_amdgcn_mfma_f32_16x16x32_bf16(qf[i][kf], k0, sacc[i][0], 0, 0, 0);
        sacc[i][1] = __builtin_amdgcn_mfma_f32_16x16x32_bf16(qf[i][kf], k1, sacc[i][1], 0, 0, 0);
      }
    }

    const bool diag = (kt == qb);
#pragma unroll
    for (int i = 0; i < 2; ++i) {
      float p0[4], p1[4], tm[4];
#pragma unroll
      for (int r = 0; r < 4; ++r) {
        float a = sacc[i][0][r], b = sacc[i][1][r];
        if (diag) {
          int row = i * 16 + quad * 4 + r;
          if (lrow > row) a = -INFINITY;
          if (lrow + 16 > row) b = -INFINITY;
        }
        p0[r] = a; p1[r] = b;
        tm[r] = fmaxf(a, b);
      }
#pragma unroll
      for (int msk = 1; msk <= 8; msk <<= 1)
#pragma unroll
        for (int r = 0; r < 4; ++r) tm[r] = fmaxf(tm[r], __shfl_xor(tm[r], msk, 64));
      float rs[4];
#pragma unroll
      for (int r = 0; r < 4; ++r) {
        float nm = fmaxf(mrun[i][r], tm[r]);
        float alpha = exp2f((mrun[i][r] - nm) * L2E);
        mrun[i][r] = nm;
        p0[r] = exp2f((p0[r] - nm) * L2E);
        p1[r] = exp2f((p1[r] - nm) * L2E);
        rs[r] = p0[r] + p1[r];
        lrun[i][r] *= alpha;
#pragma unroll
        for (int jd = 0; jd < 8; ++jd) O[i][jd][r] *= alpha;
      }
#pragma unroll
      for (int msk = 1; msk <= 8; msk <<= 1)
#pragma unroll
        for (int r = 0; r < 4; ++r) rs[r] += __shfl_xor(rs[r], msk, 64);
#pragma unroll
      for (int r = 0; r < 4; ++r) {
        lrun[i][r] += rs[r];
        Ps[wave][(i * 16 + quad * 4 + r) * 32 + lrow] = f2bf(p0[r]);
        Ps[wave][(i * 16 + quad * 4 + r) * 32 + 16 + lrow] = f2bf(p1[r]);
      }
    }

    bf16x8 vb[8];
#pragma unroll
    for (int jd = 0; jd < 8; ++jd)
      vb[jd] = *(const bf16x8*)&Vs[(jd * 16 + lrow) * 32 + quad * 8];
#pragma unroll
    for (int i = 0; i < 2; ++i) {
      bf16x8 pa = *(const bf16x8*)&Ps[wave][(i * 16 + lrow) * 32 + quad * 8];
#pragma unroll
      for (int jd = 0; jd < 8; ++jd)
        O[i][jd] = __builtin_amdgcn_mfma_f32_16x16x32_bf16(pa, vb[jd], O[i][jd], 0, 0, 0);
    }
    __syncthreads();
  }

#pragma unroll
  for (int i = 0; i < 2; ++i)
#pragma unroll
    for (int r = 0; r < 4; ++r) {
      float inv = 1.f / lrun[i][r];
      int row = qb * 32 + i * 16 + quad * 4 + r;
#pragma unroll
      for (int jd = 0; jd < 8; ++jd)
        out[(size_t)row * DMODEL + h * HDIM + jd * 16 + lrow] = f2bf(O[i][jd][r] * inv);
    }
}

extern "C" void kernel_launch(void* const* d_in, const int* in_sizes, int n_in,
                              void* d_out, int out_size, void* d_ws, size_t ws_size,
                              hipStream_t stream) {
  const float* hs   = (const float*)d_in[0];
  const float* cosb = (const float*)d_in[1];
  const float* sinb = (const float*)d_in[2];
  const float* Wq   = (const float*)d_in[5];
  const float* Wk   = (const float*)d_in[6];
  const float* Wv   = (const float*)d_in[7];
  const float* Wo   = (const float*)d_in[8];
  const float* rmsw = (const float*)d_in[9];

  float* outp = (float*)d_out;
  float* kc = outp + (size_t)S_LEN * DMODEL;
  float* vc = kc + (size_t)MAXSEQ * NKV * HDIM;

  char* p = (char*)d_ws;
  short* h_bf  = (short*)p; p += (size_t)S_LEN * DMODEL * 2;
  short* WqkvT = (short*)p; p += (size_t)NQKV * DMODEL * 2;
  short* WoT   = (short*)p; p += (size_t)DMODEL * DMODEL * 2;
  float* QKV   = (float*)p; p += (size_t)S_LEN * NQKV * 4;
  short* q_bf  = (short*)p; p += (size_t)NHEAD * S_LEN * HDIM * 2;
  short* k_bf  = (short*)p; p += (size_t)NKV * S_LEN * HDIM * 2;
  short* vt_bf = (short*)p; p += (size_t)NKV * HDIM * S_LEN * 2;
  short* attn_bf = h_bf;  // alias: h consumed by gemm1 before attention writes

  rmsnorm_kernel<<<S_LEN, 256, 0, stream>>>(hs, rmsw, h_bf);
  cast_transpose<<<dim3(DMODEL / 32, DMODEL / 32), dim3(32, 8), 0, stream>>>(Wq, WqkvT, DMODEL, DMODEL);
  cast_transpose<<<dim3(1024 / 32, DMODEL / 32), dim3(32, 8), 0, stream>>>(Wk, WqkvT + (size_t)DMODEL * DMODEL, DMODEL, 1024);
  cast_transpose<<<dim3(1024 / 32, DMODEL / 32), dim3(32, 8), 0, stream>>>(Wv, WqkvT + (size_t)5120 * DMODEL, DMODEL, 1024);
  cast_transpose<<<dim3(DMODEL / 32, DMODEL / 32), dim3(32, 8), 0, stream>>>(Wo, WoT, DMODEL, DMODEL);
  gemm_bt<<<dim3(NQKV / 128, S_LEN / 128), 256, 0, stream>>>(h_bf, WqkvT, QKV, nullptr, S_LEN, NQKV, DMODEL);
  rope_kernel<<<S_LEN, 256, 0, stream>>>(QKV, cosb, sinb, q_bf, k_bf, vt_bf, kc, vc);
  zero_tail<<<4096, 256, 0, stream>>>(kc, vc);
  attn_kernel<<<dim3(S_LEN / 32, NKV), 256, 0, stream>>>(q_bf, k_bf, vt_bf, attn_bf);
  gemm_bt<<<dim3(DMODEL / 128, S_LEN / 128), 256, 0, stream>>>(attn_bf, WoT, outp, hs, S_LEN, DMODEL, DMODEL);
}

// Round 2
// 672.373 us; speedup vs baseline: 1.1685x; 1.1685x over previous
//
#include <hip/hip_runtime.h>
#include <hip/hip_bf16.h>
#include <cstdint>

#define S_LEN 2048
#define DMODEL 4096
#define NHEAD 32
#define NKV 8
#define HDIM 128
#define MAXSEQ 4096
#define NQKV 6144   // 4096 + 1024 + 1024

typedef __bf16 bf16x8 __attribute__((ext_vector_type(8)));
typedef float f32x4 __attribute__((ext_vector_type(4)));
typedef short s16x4 __attribute__((ext_vector_type(4)));

__device__ __forceinline__ short f2bf(float f) {
  unsigned u = __builtin_bit_cast(unsigned, f);
  u += 0x7fffu + ((u >> 16) & 1u);
  return (short)(u >> 16);
}

__device__ __forceinline__ void gload_lds16(const void* g, const void* l) {
  __builtin_amdgcn_global_load_lds((const __attribute__((address_space(1))) unsigned*)g,
                                   (__attribute__((address_space(3))) unsigned*)(l), 16, 0, 0);
}

// ---------------- RMSNorm: fp32 in -> bf16 out ----------------
__global__ __launch_bounds__(256) void rmsnorm_kernel(const float* __restrict__ x,
                                                      const float* __restrict__ w,
                                                      short* __restrict__ out) {
  const int row = blockIdx.x, tid = threadIdx.x;
  const float4* xr = (const float4*)(x + (size_t)row * DMODEL);
  const float4* wr = (const float4*)w;
  float4 v[4];
  float ss = 0.f;
#pragma unroll
  for (int i = 0; i < 4; ++i) {
    v[i] = xr[tid + i * 256];
    ss += v[i].x * v[i].x + v[i].y * v[i].y + v[i].z * v[i].z + v[i].w * v[i].w;
  }
#pragma unroll
  for (int m = 32; m; m >>= 1) ss += __shfl_down(ss, m, 64);
  __shared__ float red[4];
  if ((tid & 63) == 0) red[tid >> 6] = ss;
  __syncthreads();
  float tot = red[0] + red[1] + red[2] + red[3];
  float sc = rsqrtf(tot * (1.f / DMODEL) + 1e-5f);
#pragma unroll
  for (int i = 0; i < 4; ++i) {
    float4 wv = wr[tid + i * 256];
    s16x4 o;
    o[0] = f2bf(v[i].x * sc * wv.x);
    o[1] = f2bf(v[i].y * sc * wv.y);
    o[2] = f2bf(v[i].z * sc * wv.z);
    o[3] = f2bf(v[i].w * sc * wv.w);
    *(s16x4*)&out[(size_t)row * DMODEL + (size_t)(tid + i * 256) * 4] = o;
  }
}

// ---------------- cast fp32 (rows x cols) -> bf16 transposed (cols x rows) ----------------
__global__ __launch_bounds__(256) void cast_transpose(const float* __restrict__ src,
                                                      short* __restrict__ dst,
                                                      int rows, int cols) {
  __shared__ float tile[32][33];
  const int c0 = blockIdx.x * 32, r0 = blockIdx.y * 32;
  const int tx = threadIdx.x, ty = threadIdx.y;
#pragma unroll
  for (int i = ty; i < 32; i += 8) tile[i][tx] = src[(size_t)(r0 + i) * cols + c0 + tx];
  __syncthreads();
#pragma unroll
  for (int i = ty; i < 32; i += 8)
    dst[(size_t)(c0 + i) * rows + r0 + tx] = f2bf(tile[tx][i]);
}

// ---------------- bf16 MFMA GEMM: C(MxN fp32) = A(MxK) * Bt(NxK)^T  (+ optional residual) ----------------
__global__ __launch_bounds__(256, 2) void gemm_bt(const short* __restrict__ A,
                                                  const short* __restrict__ Bt,
                                                  float* __restrict__ C,
                                                  const float* __restrict__ resid,
                                                  int M, int N, int K) {
  __shared__ __align__(16) short As[128 * 64];
  __shared__ __align__(16) short Bs[128 * 64];
  const int tid = threadIdx.x;
  const int lane = tid & 63, wave = tid >> 6;
  const int wr = wave >> 1, wc = wave & 1;
  const int lrow = lane & 15, quad = lane >> 4;
  const int m0 = blockIdx.y * 128, n0 = blockIdx.x * 128;
  f32x4 acc[4][4] = {};
  for (int k0 = 0; k0 < K; k0 += 64) {
#pragma unroll
    for (int c = 0; c < 4; ++c) {
      int idx = (wave * 4 + c) * 512 + lane * 8;
      int row = idx >> 6, kc = idx & 63;
      gload_lds16(A + (size_t)(m0 + row) * K + k0 + kc, &As[(wave * 4 + c) * 512]);
      gload_lds16(Bt + (size_t)(n0 + row) * K + k0 + kc, &Bs[(wave * 4 + c) * 512]);
    }
    __syncthreads();
#pragma unroll
    for (int kk = 0; kk < 2; ++kk) {
      bf16x8 af[4], bfr[4];
#pragma unroll
      for (int i = 0; i < 4; ++i)
        af[i] = *(const bf16x8*)&As[(wr * 64 + i * 16 + lrow) * 64 + kk * 32 + quad * 8];
#pragma unroll
      for (int j = 0; j < 4; ++j)
        bfr[j] = *(const bf16x8*)&Bs[(wc * 64 + j * 16 + lrow) * 64 + kk * 32 + quad * 8];
#pragma unroll
      for (int i = 0; i < 4; ++i)
#pragma unroll
        for (int j = 0; j < 4; ++j)
          acc[i][j] = __builtin_amdgcn_mfma_f32_16x16x32_bf16(af[i], bfr[j], acc[i][j], 0, 0, 0);
    }
    __syncthreads();
  }
#pragma unroll
  for (int i = 0; i < 4; ++i)
#pragma unroll
    for (int j = 0; j < 4; ++j) {
      int row = m0 + wr * 64 + i * 16 + quad * 4;
      int col = n0 + wc * 64 + j * 16 + lrow;
#pragma unroll
      for (int r = 0; r < 4; ++r) {
        float v = acc[i][j][r];
        size_t o = (size_t)(row + r) * N + col;
        if (resid) v += resid[o];
        C[o] = v;
      }
    }
}

// ---------------- RoPE (interleaved) + cache write + attention-layout staging ----------------
__global__ __launch_bounds__(256) void rope_kernel(const float* __restrict__ QKV,
                                                   const float* __restrict__ cosb,
                                                   const float* __restrict__ sinb,
                                                   short* __restrict__ qo,
                                                   short* __restrict__ ko,
                                                   short* __restrict__ vt,
                                                   float* __restrict__ kc,
                                                   float* __restrict__ vc) {
  const int s = blockIdx.x, tid = threadIdx.x;
  const float* row = QKV + (size_t)s * NQKV;
  const float* cr = cosb + (size_t)s * HDIM;
  const float* sr = sinb + (size_t)s * HDIM;
  const float qscale = 0.08838834764831845f;  // 1/sqrt(128) folded into Q
  for (int p = tid; p < NHEAD * 64; p += 256) {
    int hh = p >> 6, d = (p & 63) * 2;
    float x0 = row[hh * HDIM + d], x1 = row[hh * HDIM + d + 1];
    float c = cr[d], si = sr[d];
    float o0 = (x0 * c - x1 * si) * qscale;
    float o1 = (x1 * c + x0 * si) * qscale;
    size_t o = ((size_t)hh * S_LEN + s) * HDIM + d;
    qo[o] = f2bf(o0);
    qo[o + 1] = f2bf(o1);
  }
  for (int p = tid; p < NKV * 64; p += 256) {
    int g = p >> 6, d = (p & 63) * 2;
    float x0 = row[NHEAD * HDIM + g * HDIM + d], x1 = row[NHEAD * HDIM + g * HDIM + d + 1];
    float c = cr[d], si = sr[d];
    float o0 = x0 * c - x1 * si;
    float o1 = x1 * c + x0 * si;
    size_t o = ((size_t)g * S_LEN + s) * HDIM + d;
    ko[o] = f2bf(o0);
    ko[o + 1] = f2bf(o1);
    kc[(size_t)s * (NKV * HDIM) + g * HDIM + d] = o0;
    kc[(size_t)s * (NKV * HDIM) + g * HDIM + d + 1] = o1;
  }
  for (int e = tid; e < NKV * HDIM; e += 256) {
    int g = e >> 7, d = e & 127;
    float v = row[(NHEAD + NKV) * HDIM + e];
    vc[(size_t)s * (NKV * HDIM) + e] = v;
    vt[((size_t)g * HDIM + d) * S_LEN + s] = f2bf(v);
  }
}

// ---------------- zero cache tail rows [S_LEN, MAXSEQ) ----------------
__global__ __launch_bounds__(256) void zero_tail(float* __restrict__ kc, float* __restrict__ vc) {
  size_t i = (size_t)blockIdx.x * 256 + threadIdx.x;
  const size_t tail4 = (size_t)(MAXSEQ - S_LEN) * NKV * HDIM / 4;  // 524288
  float4 z = make_float4(0.f, 0.f, 0.f, 0.f);
  float4* kt = (float4*)(kc + (size_t)S_LEN * NKV * HDIM);
  float4* vt = (float4*)(vc + (size_t)S_LEN * NKV * HDIM);
  if (i < tail4) kt[i] = z;
  else if (i < 2 * tail4) vt[i - tail4] = z;
}

// ---------------- GQA causal flash attention v2 ----------------
// 1D grid 256 blocks: g = bid&7 (XCD-pinned KV group), p = bid>>3 -> q-tiles {p, 63-p}
// 256 threads = 4 waves = 4 heads of the group, 32 q-rows per wave.
// 128-key tiles, double-buffered global_load_lds staging, swizzled LDS granules.
#define TKEY 128
__global__ __launch_bounds__(256, 1) void attn_kernel(const short* __restrict__ Q,
                                                      const short* __restrict__ Kb,
                                                      const short* __restrict__ Vt,
                                                      short* __restrict__ out) {
  extern __shared__ __align__(16) short smem[];
  short* Ks = smem;            // 2 * 128*128
  short* Vs = smem + 32768;    // 2 * 128*128
  short* Ps = smem + 65536;    // 4 waves * 32*32
  const int tid = threadIdx.x;
  const int lane = tid & 63, wave = tid >> 6;
  const int lrow = lane & 15, quad = lane >> 4;
  const int g = blockIdx.x & 7, p = blockIdx.x >> 3;
  const int h = g * 4 + wave;
  const float L2E = 1.44269504f;
  const short* Kg = Kb + (size_t)g * S_LEN * HDIM;
  const short* Vg = Vt + (size_t)g * HDIM * S_LEN;
  short* Pw = Ps + wave * 1024;

#pragma unroll 1
  for (int ph = 0; ph < 2; ++ph) {
    const int qt = ph ? (63 - p) : p;
    const int nt = (qt >> 2) + 1;  // # of 128-key tiles

    bf16x8 qf[2][4];
#pragma unroll
    for (int i = 0; i < 2; ++i)
#pragma unroll
      for (int kf = 0; kf < 4; ++kf)
        qf[i][kf] = *(const bf16x8*)&Q[((size_t)h * S_LEN + qt * 32 + i * 16 + lrow) * HDIM + kf * 32 + quad * 8];

    f32x4 O[2][8] = {};
    float mrun[2][4], lrun[2][4];
#pragma unroll
    for (int i = 0; i < 2; ++i)
#pragma unroll
      for (int r = 0; r < 4; ++r) { mrun[i][r] = -1e30f; lrun[i][r] = 0.f; }

    // stage tile 0 into buffer 0: K 2048 granules + V 2048 granules, 8+8 instr/wave
#pragma unroll
    for (int ii = 0; ii < 8; ++ii) {
      int s = (wave * 8 + ii) * 64 + lane;
      int r = s >> 4, gg = (s & 15) ^ (r & 15);
      gload_lds16(Kg + (size_t)r * HDIM + gg * 8, Ks + (wave * 8 + ii) * 512);
    }
#pragma unroll
    for (int ii = 0; ii < 8; ++ii) {
      int s = (wave * 8 + ii) * 64 + lane;
      int d = s >> 4, kg = (s & 15) ^ (d & 15);
      gload_lds16(Vg + (size_t)d * S_LEN + kg * 8, Vs + (wave * 8 + ii) * 512);
    }
    __syncthreads();

#pragma unroll 1
    for (int t = 0; t < nt; ++t) {
      const int bsel = t & 1;
      // prefetch tile t+1 into other buffer (overlaps with compute below)
      if (t + 1 < nt) {
        const int kb2 = (t + 1) * TKEY, o = (1 - bsel) * 16384;
#pragma unroll
        for (int ii = 0; ii < 8; ++ii) {
          int s = (wave * 8 + ii) * 64 + lane;
          int r = s >> 4, gg = (s & 15) ^ (r & 15);
          gload_lds16(Kg + (size_t)(kb2 + r) * HDIM + gg * 8, Ks + o + (wave * 8 + ii) * 512);
        }
#pragma unroll
        for (int ii = 0; ii < 8; ++ii) {
          int s = (wave * 8 + ii) * 64 + lane;
          int d = s >> 4, kg = (s & 15) ^ (d & 15);
          gload_lds16(Vg + (size_t)d * S_LEN + kb2 + kg * 8, Vs + o + (wave * 8 + ii) * 512);
        }
      }
      const short* Kc = Ks + bsel * 16384;
      const short* Vc = Vs + bsel * 16384;

      // ---- QK^T: 32 rows x 128 keys ----
      f32x4 sc[2][8] = {};
#pragma unroll
      for (int c = 0; c < 8; ++c) {
        int r = c * 16 + lrow;
#pragma unroll
        for (int kf = 0; kf < 4; ++kf) {
          int slot = r * 16 + ((kf * 4 + quad) ^ lrow);
          bf16x8 kfr = *(const bf16x8*)&Kc[slot * 8];
          sc[0][c] = __builtin_amdgcn_mfma_f32_16x16x32_bf16(qf[0][kf], kfr, sc[0][c], 0, 0, 0);
          sc[1][c] = __builtin_amdgcn_mfma_f32_16x16x32_bf16(qf[1][kf], kfr, sc[1][c], 0, 0, 0);
        }
      }

      // ---- online softmax ----
      const int kb = t * TKEY;
      const bool last = (t == nt - 1);
#pragma unroll
      for (int i = 0; i < 2; ++i) {
        if (last) {
#pragma unroll
          for (int c = 0; c < 8; ++c) {
            int key = kb + c * 16 + lrow;
#pragma unroll
            for (int r = 0; r < 4; ++r) {
              int row = qt * 32 + i * 16 + quad * 4 + r;
              if (key > row) sc[i][c][r] = -1e30f;
            }
          }
        }
        float tm[4];
#pragma unroll
        for (int r = 0; r < 4; ++r) tm[r] = sc[i][0][r];
#pragma unroll
        for (int c = 1; c < 8; ++c)
#pragma unroll
          for (int r = 0; r < 4; ++r) tm[r] = fmaxf(tm[r], sc[i][c][r]);
#pragma unroll
        for (int msk = 1; msk <= 8; msk <<= 1)
#pragma unroll
          for (int r = 0; r < 4; ++r) tm[r] = fmaxf(tm[r], __shfl_xor(tm[r], msk, 64));
#pragma unroll
        for (int r = 0; r < 4; ++r) {
          float nm = fmaxf(mrun[i][r], tm[r]);
          float alpha = exp2f((mrun[i][r] - nm) * L2E);
          mrun[i][r] = nm;
          lrun[i][r] *= alpha;
#pragma unroll
          for (int jd = 0; jd < 8; ++jd) O[i][jd][r] *= alpha;
        }
        float rs[4] = {0.f, 0.f, 0.f, 0.f};
#pragma unroll
        for (int c = 0; c < 8; ++c)
#pragma unroll
          for (int r = 0; r < 4; ++r) {
            float pv = exp2f((sc[i][c][r] - mrun[i][r]) * L2E);
            sc[i][c][r] = pv;
            rs[r] += pv;
          }
#pragma unroll
        for (int msk = 1; msk <= 8; msk <<= 1)
#pragma unroll
          for (int r = 0; r < 4; ++r) rs[r] += __shfl_xor(rs[r], msk, 64);
#pragma unroll
        for (int r = 0; r < 4; ++r) lrun[i][r] += rs[r];
      }

      // ---- P·V in 32-key chunks (per-wave Ps transpose buffer, swizzled) ----
#pragma unroll
      for (int ks = 0; ks < 4; ++ks) {
        // write P chunk: c-frags 2ks, 2ks+1
#pragma unroll
        for (int i = 0; i < 2; ++i)
#pragma unroll
          for (int cc = 0; cc < 2; ++cc) {
            int c = ks * 2 + cc;
            int kg = cc * 2 + (lrow >> 3), off = lrow & 7;
#pragma unroll
            for (int r = 0; r < 4; ++r) {
              int q2 = i * 16 + quad * 4 + r;
              int slot = q2 * 4 + (kg ^ (q2 & 3) ^ ((q2 >> 2) & 3));
              Pw[slot * 8 + off] = f2bf(sc[i][c][r]);
            }
          }
        bf16x8 pa[2];
#pragma unroll
        for (int i = 0; i < 2; ++i) {
          int q2 = i * 16 + lrow;
          int slot = q2 * 4 + (quad ^ (q2 & 3) ^ ((q2 >> 2) & 3));
          pa[i] = *(const bf16x8*)&Pw[slot * 8];
        }
#pragma unroll
        for (int jd = 0; jd < 8; ++jd) {
          int d = jd * 16 + lrow;
          int slotv = d * 16 + ((ks * 4 + quad) ^ lrow);
          bf16x8 vb = *(const bf16x8*)&Vc[slotv * 8];
          O[0][jd] = __builtin_amdgcn_mfma_f32_16x16x32_bf16(pa[0], vb, O[0][jd], 0, 0, 0);
          O[1][jd] = __builtin_amdgcn_mfma_f32_16x16x32_bf16(pa[1], vb, O[1][jd], 0, 0, 0);
        }
      }
      __syncthreads();
    }

    // ---- epilogue ----
#pragma unroll
    for (int i = 0; i < 2; ++i)
#pragma unroll
      for (int r = 0; r < 4; ++r) {
        float inv = 1.f / lrun[i][r];
        int row = qt * 32 + i * 16 + quad * 4 + r;
#pragma unroll
        for (int jd = 0; jd < 8; ++jd)
          out[(size_t)row * DMODEL + h * HDIM + jd * 16 + lrow] = f2bf(O[i][jd][r] * inv);
      }
    __syncthreads();  // Ks/Vs safe for next phase's staging
  }
}

extern "C" void kernel_launch(void* const* d_in, const int* in_sizes, int n_in,
                              void* d_out, int out_size, void* d_ws, size_t ws_size,
                              hipStream_t stream) {
  const float* hs   = (const float*)d_in[0];
  const float* cosb = (const float*)d_in[1];
  const float* sinb = (const float*)d_in[2];
  const float* Wq   = (const float*)d_in[5];
  const float* Wk   = (const float*)d_in[6];
  const float* Wv   = (const float*)d_in[7];
  const float* Wo   = (const float*)d_in[8];
  const float* rmsw = (const float*)d_in[9];

  float* outp = (float*)d_out;
  float* kc = outp + (size_t)S_LEN * DMODEL;
  float* vc = kc + (size_t)MAXSEQ * NKV * HDIM;

  char* p = (char*)d_ws;
  short* h_bf  = (short*)p; p += (size_t)S_LEN * DMODEL * 2;
  short* WqkvT = (short*)p; p += (size_t)NQKV * DMODEL * 2;
  short* WoT   = (short*)p; p += (size_t)DMODEL * DMODEL * 2;
  float* QKV   = (float*)p; p += (size_t)S_LEN * NQKV * 4;
  short* q_bf  = (short*)p; p += (size_t)NHEAD * S_LEN * HDIM * 2;
  short* k_bf  = (short*)p; p += (size_t)NKV * S_LEN * HDIM * 2;
  short* vt_bf = (short*)p; p += (size_t)NKV * HDIM * S_LEN * 2;
  short* attn_bf = h_bf;  // alias: h consumed by gemm1 before attention writes

  const int ATTN_LDS = 139264;  // 64KB K dbuf + 64KB V dbuf + 8KB P
  hipFuncSetAttribute(reinterpret_cast<const void*>(attn_kernel),
                      hipFuncAttributeMaxDynamicSharedMemorySize, ATTN_LDS);

  rmsnorm_kernel<<<S_LEN, 256, 0, stream>>>(hs, rmsw, h_bf);
  cast_transpose<<<dim3(DMODEL / 32, DMODEL / 32), dim3(32, 8), 0, stream>>>(Wq, WqkvT, DMODEL, DMODEL);
  cast_transpose<<<dim3(1024 / 32, DMODEL / 32), dim3(32, 8), 0, stream>>>(Wk, WqkvT + (size_t)DMODEL * DMODEL, DMODEL, 1024);
  cast_transpose<<<dim3(1024 / 32, DMODEL / 32), dim3(32, 8), 0, stream>>>(Wv, WqkvT + (size_t)5120 * DMODEL, DMODEL, 1024);
  cast_transpose<<<dim3(DMODEL / 32, DMODEL / 32), dim3(32, 8), 0, stream>>>(Wo, WoT, DMODEL, DMODEL);
  gemm_bt<<<dim3(NQKV / 128, S_LEN / 128), 256, 0, stream>>>(h_bf, WqkvT, QKV, nullptr, S_LEN, NQKV, DMODEL);
  rope_kernel<<<S_LEN, 256, 0, stream>>>(QKV, cosb, sinb, q_bf, k_bf, vt_bf, kc, vc);
  zero_tail<<<4096, 256, 0, stream>>>(kc, vc);
  attn_kernel<<<256, 256, ATTN_LDS, stream>>>(q_bf, k_bf, vt_bf, attn_bf);
  gemm_bt<<<dim3(DMODEL / 128, S_LEN / 128), 256, 0, stream>>>(attn_bf, WoT, outp, hs, S_LEN, DMODEL, DMODEL);
}

// Round 3
// 664.960 us; speedup vs baseline: 1.1815x; 1.0111x over previous
//
#include <hip/hip_runtime.h>
#include <hip/hip_bf16.h>
#include <cstdint>

#define S_LEN 2048
#define DMODEL 4096
#define NHEAD 32
#define NKV 8
#define HDIM 128
#define MAXSEQ 4096
#define NQKV 6144   // 4096 + 1024 + 1024

typedef __bf16 bf16x8 __attribute__((ext_vector_type(8)));
typedef float f32x4 __attribute__((ext_vector_type(4)));
typedef short s16x4 __attribute__((ext_vector_type(4)));

__device__ __forceinline__ short f2bf(float f) {
  unsigned u = __builtin_bit_cast(unsigned, f);
  u += 0x7fffu + ((u >> 16) & 1u);
  return (short)(u >> 16);
}

__device__ __forceinline__ void gload_lds16(const void* g, const void* l) {
  __builtin_amdgcn_global_load_lds((const __attribute__((address_space(1))) unsigned*)g,
                                   (__attribute__((address_space(3))) unsigned*)(l), 16, 0, 0);
}

// ---------------- RMSNorm: fp32 in -> bf16 out ----------------
__global__ __launch_bounds__(256) void rmsnorm_kernel(const float* __restrict__ x,
                                                      const float* __restrict__ w,
                                                      short* __restrict__ out) {
  const int row = blockIdx.x, tid = threadIdx.x;
  const float4* xr = (const float4*)(x + (size_t)row * DMODEL);
  const float4* wr = (const float4*)w;
  float4 v[4];
  float ss = 0.f;
#pragma unroll
  for (int i = 0; i < 4; ++i) {
    v[i] = xr[tid + i * 256];
    ss += v[i].x * v[i].x + v[i].y * v[i].y + v[i].z * v[i].z + v[i].w * v[i].w;
  }
#pragma unroll
  for (int m = 32; m; m >>= 1) ss += __shfl_down(ss, m, 64);
  __shared__ float red[4];
  if ((tid & 63) == 0) red[tid >> 6] = ss;
  __syncthreads();
  float tot = red[0] + red[1] + red[2] + red[3];
  float sc = rsqrtf(tot * (1.f / DMODEL) + 1e-5f);
#pragma unroll
  for (int i = 0; i < 4; ++i) {
    float4 wv = wr[tid + i * 256];
    s16x4 o;
    o[0] = f2bf(v[i].x * sc * wv.x);
    o[1] = f2bf(v[i].y * sc * wv.y);
    o[2] = f2bf(v[i].z * sc * wv.z);
    o[3] = f2bf(v[i].w * sc * wv.w);
    *(s16x4*)&out[(size_t)row * DMODEL + (size_t)(tid + i * 256) * 4] = o;
  }
}

// ---------------- cast fp32 (rows x cols) -> bf16 transposed (cols x rows) ----------------
__global__ __launch_bounds__(256) void cast_transpose(const float* __restrict__ src,
                                                      short* __restrict__ dst,
                                                      int rows, int cols) {
  __shared__ float tile[32][33];
  const int c0 = blockIdx.x * 32, r0 = blockIdx.y * 32;
  const int tx = threadIdx.x, ty = threadIdx.y;
#pragma unroll
  for (int i = ty; i < 32; i += 8) tile[i][tx] = src[(size_t)(r0 + i) * cols + c0 + tx];
  __syncthreads();
#pragma unroll
  for (int i = ty; i < 32; i += 8)
    dst[(size_t)(c0 + i) * rows + r0 + tx] = f2bf(tile[tx][i]);
}

// ---------------- V transpose: QKV V-region fp32 -> vc fp32 (natural) + vt bf16 [g][d][s] ----------------
// grid (HDIM/32, S_LEN/32, NKV), block (32,8). Coalesced on both sides.
__global__ __launch_bounds__(256) void v_transpose(const float* __restrict__ QKV,
                                                   float* __restrict__ vc,
                                                   short* __restrict__ vt) {
  __shared__ float tile[32][33];
  const int d0 = blockIdx.x * 32, s0 = blockIdx.y * 32, g = blockIdx.z;
  const int tx = threadIdx.x, ty = threadIdx.y;
#pragma unroll
  for (int i = ty; i < 32; i += 8) {
    float v = QKV[(size_t)(s0 + i) * NQKV + (NHEAD + NKV) * HDIM + g * HDIM + d0 + tx];
    tile[i][tx] = v;
    vc[(size_t)(s0 + i) * (NKV * HDIM) + g * HDIM + d0 + tx] = v;
  }
  __syncthreads();
#pragma unroll
  for (int i = ty; i < 32; i += 8)
    vt[((size_t)g * HDIM + d0 + i) * S_LEN + s0 + tx] = f2bf(tile[tx][i]);
}

// ---------------- bf16 MFMA GEMM: C(MxN fp32) = A(MxK) * Bt(NxK)^T  (+ optional residual) ----------------
__global__ __launch_bounds__(256, 2) void gemm_bt(const short* __restrict__ A,
                                                  const short* __restrict__ Bt,
                                                  float* __restrict__ C,
                                                  const float* __restrict__ resid,
                                                  int M, int N, int K) {
  __shared__ __align__(16) short As[128 * 64];
  __shared__ __align__(16) short Bs[128 * 64];
  const int tid = threadIdx.x;
  const int lane = tid & 63, wave = tid >> 6;
  const int wr = wave >> 1, wc = wave & 1;
  const int lrow = lane & 15, quad = lane >> 4;
  const int m0 = blockIdx.y * 128, n0 = blockIdx.x * 128;
  f32x4 acc[4][4] = {};
  for (int k0 = 0; k0 < K; k0 += 64) {
#pragma unroll
    for (int c = 0; c < 4; ++c) {
      int idx = (wave * 4 + c) * 512 + lane * 8;
      int row = idx >> 6, kc = idx & 63;
      gload_lds16(A + (size_t)(m0 + row) * K + k0 + kc, &As[(wave * 4 + c) * 512]);
      gload_lds16(Bt + (size_t)(n0 + row) * K + k0 + kc, &Bs[(wave * 4 + c) * 512]);
    }
    __syncthreads();
#pragma unroll
    for (int kk = 0; kk < 2; ++kk) {
      bf16x8 af[4], bfr[4];
#pragma unroll
      for (int i = 0; i < 4; ++i)
        af[i] = *(const bf16x8*)&As[(wr * 64 + i * 16 + lrow) * 64 + kk * 32 + quad * 8];
#pragma unroll
      for (int j = 0; j < 4; ++j)
        bfr[j] = *(const bf16x8*)&Bs[(wc * 64 + j * 16 + lrow) * 64 + kk * 32 + quad * 8];
#pragma unroll
      for (int i = 0; i < 4; ++i)
#pragma unroll
        for (int j = 0; j < 4; ++j)
          acc[i][j] = __builtin_amdgcn_mfma_f32_16x16x32_bf16(af[i], bfr[j], acc[i][j], 0, 0, 0);
    }
    __syncthreads();
  }
#pragma unroll
  for (int i = 0; i < 4; ++i)
#pragma unroll
    for (int j = 0; j < 4; ++j) {
      int row = m0 + wr * 64 + i * 16 + quad * 4;
      int col = n0 + wc * 64 + j * 16 + lrow;
#pragma unroll
      for (int r = 0; r < 4; ++r) {
        float v = acc[i][j][r];
        size_t o = (size_t)(row + r) * N + col;
        if (resid) v += resid[o];
        C[o] = v;
      }
    }
}

// ---------------- RoPE (interleaved) for Q and K, vectorized; writes q_bf, k_bf, kc ----------------
__global__ __launch_bounds__(256) void rope_kernel(const float* __restrict__ QKV,
                                                   const float* __restrict__ cosb,
                                                   const float* __restrict__ sinb,
                                                   short* __restrict__ qo,
                                                   short* __restrict__ ko,
                                                   float* __restrict__ kc) {
  const int s = blockIdx.x, tid = threadIdx.x;
  const float4* r4 = (const float4*)(QKV + (size_t)s * NQKV);
  const float qscale = 0.08838834764831845f;  // 1/sqrt(128) folded into Q
  // (4096 q + 1024 k) floats = 1280 float4; 5 iters of 256 threads; boundary at iter 4 (wave-uniform)
#pragma unroll
  for (int it = 0; it < 5; ++it) {
    int i = it * 256 + tid;
    float4 x = r4[i];
    int e = i * 4;            // flat float index within row
    int d = e & 127;          // dim within head (heads are 128-aligned)
    float4 c = *(const float4*)&cosb[(size_t)s * HDIM + d];
    float4 si = *(const float4*)&sinb[(size_t)s * HDIM + d];
    float o0 = x.x * c.x - x.y * si.x;
    float o1 = x.y * c.y + x.x * si.y;
    float o2 = x.z * c.z - x.w * si.z;
    float o3 = x.w * c.w + x.z * si.w;
    if (e < NHEAD * HDIM) {
      int hh = e >> 7;
      s16x4 ov;
      ov[0] = f2bf(o0 * qscale); ov[1] = f2bf(o1 * qscale);
      ov[2] = f2bf(o2 * qscale); ov[3] = f2bf(o3 * qscale);
      *(s16x4*)&qo[((size_t)hh * S_LEN + s) * HDIM + d] = ov;
    } else {
      int ek = e - NHEAD * HDIM;
      int g = ek >> 7;
      s16x4 ov;
      ov[0] = f2bf(o0); ov[1] = f2bf(o1); ov[2] = f2bf(o2); ov[3] = f2bf(o3);
      *(s16x4*)&ko[((size_t)g * S_LEN + s) * HDIM + d] = ov;
      *(float4*)&kc[(size_t)s * (NKV * HDIM) + ek] = make_float4(o0, o1, o2, o3);
    }
  }
}

// ---------------- zero cache tail rows [S_LEN, MAXSEQ) ----------------
__global__ __launch_bounds__(256) void zero_tail(float* __restrict__ kc, float* __restrict__ vc) {
  size_t i = (size_t)blockIdx.x * 256 + threadIdx.x;
  const size_t tail4 = (size_t)(MAXSEQ - S_LEN) * NKV * HDIM / 4;  // 524288
  float4 z = make_float4(0.f, 0.f, 0.f, 0.f);
  float4* kt = (float4*)(kc + (size_t)S_LEN * NKV * HDIM);
  float4* vt = (float4*)(vc + (size_t)S_LEN * NKV * HDIM);
  if (i < tail4) kt[i] = z;
  else if (i < 2 * tail4) vt[i - tail4] = z;
}

// ---------------- GQA causal flash attention v2 ----------------
// 1D grid 256 blocks: g = bid&7 (XCD-pinned KV group), p = bid>>3 -> q-tiles {p, 63-p}
// 256 threads = 4 waves = 4 heads of the group, 32 q-rows per wave.
// 128-key tiles, double-buffered global_load_lds staging, swizzled LDS granules.
#define TKEY 128
__global__ __launch_bounds__(256, 1) void attn_kernel(const short* __restrict__ Q,
                                                      const short* __restrict__ Kb,
                                                      const short* __restrict__ Vt,
                                                      short* __restrict__ out) {
  extern __shared__ __align__(16) short smem[];
  short* Ks = smem;            // 2 * 128*128
  short* Vs = smem + 32768;    // 2 * 128*128
  short* Ps = smem + 65536;    // 4 waves * 32*32
  const int tid = threadIdx.x;
  const int lane = tid & 63, wave = tid >> 6;
  const int lrow = lane & 15, quad = lane >> 4;
  const int g = blockIdx.x & 7, p = blockIdx.x >> 3;
  const int h = g * 4 + wave;
  const float L2E = 1.44269504f;
  const short* Kg = Kb + (size_t)g * S_LEN * HDIM;
  const short* Vg = Vt + (size_t)g * HDIM * S_LEN;
  short* Pw = Ps + wave * 1024;

#pragma unroll 1
  for (int ph = 0; ph < 2; ++ph) {
    const int qt = ph ? (63 - p) : p;
    const int nt = (qt >> 2) + 1;  // # of 128-key tiles

    bf16x8 qf[2][4];
#pragma unroll
    for (int i = 0; i < 2; ++i)
#pragma unroll
      for (int kf = 0; kf < 4; ++kf)
        qf[i][kf] = *(const bf16x8*)&Q[((size_t)h * S_LEN + qt * 32 + i * 16 + lrow) * HDIM + kf * 32 + quad * 8];

    f32x4 O[2][8] = {};
    float mrun[2][4], lrun[2][4];
#pragma unroll
    for (int i = 0; i < 2; ++i)
#pragma unroll
      for (int r = 0; r < 4; ++r) { mrun[i][r] = -1e30f; lrun[i][r] = 0.f; }

    // stage tile 0 into buffer 0
#pragma unroll
    for (int ii = 0; ii < 8; ++ii) {
      int s = (wave * 8 + ii) * 64 + lane;
      int r = s >> 4, gg = (s & 15) ^ (r & 15);
      gload_lds16(Kg + (size_t)r * HDIM + gg * 8, Ks + (wave * 8 + ii) * 512);
    }
#pragma unroll
    for (int ii = 0; ii < 8; ++ii) {
      int s = (wave * 8 + ii) * 64 + lane;
      int d = s >> 4, kg = (s & 15) ^ (d & 15);
      gload_lds16(Vg + (size_t)d * S_LEN + kg * 8, Vs + (wave * 8 + ii) * 512);
    }
    __syncthreads();

#pragma unroll 1
    for (int t = 0; t < nt; ++t) {
      const int bsel = t & 1;
      if (t + 1 < nt) {
        const int kb2 = (t + 1) * TKEY, o = (1 - bsel) * 16384;
#pragma unroll
        for (int ii = 0; ii < 8; ++ii) {
          int s = (wave * 8 + ii) * 64 + lane;
          int r = s >> 4, gg = (s & 15) ^ (r & 15);
          gload_lds16(Kg + (size_t)(kb2 + r) * HDIM + gg * 8, Ks + o + (wave * 8 + ii) * 512);
        }
#pragma unroll
        for (int ii = 0; ii < 8; ++ii) {
          int s = (wave * 8 + ii) * 64 + lane;
          int d = s >> 4, kg = (s & 15) ^ (d & 15);
          gload_lds16(Vg + (size_t)d * S_LEN + kb2 + kg * 8, Vs + o + (wave * 8 + ii) * 512);
        }
      }
      const short* Kc = Ks + bsel * 16384;
      const short* Vc = Vs + bsel * 16384;

      // ---- QK^T: 32 rows x 128 keys ----
      f32x4 sc[2][8] = {};
#pragma unroll
      for (int c = 0; c < 8; ++c) {
        int r = c * 16 + lrow;
#pragma unroll
        for (int kf = 0; kf < 4; ++kf) {
          int slot = r * 16 + ((kf * 4 + quad) ^ lrow);
          bf16x8 kfr = *(const bf16x8*)&Kc[slot * 8];
          sc[0][c] = __builtin_amdgcn_mfma_f32_16x16x32_bf16(qf[0][kf], kfr, sc[0][c], 0, 0, 0);
          sc[1][c] = __builtin_amdgcn_mfma_f32_16x16x32_bf16(qf[1][kf], kfr, sc[1][c], 0, 0, 0);
        }
      }

      // ---- online softmax ----
      const int kb = t * TKEY;
      const bool last = (t == nt - 1);
#pragma unroll
      for (int i = 0; i < 2; ++i) {
        if (last) {
#pragma unroll
          for (int c = 0; c < 8; ++c) {
            int key = kb + c * 16 + lrow;
#pragma unroll
            for (int r = 0; r < 4; ++r) {
              int row = qt * 32 + i * 16 + quad * 4 + r;
              if (key > row) sc[i][c][r] = -1e30f;
            }
          }
        }
        float tm[4];
#pragma unroll
        for (int r = 0; r < 4; ++r) tm[r] = sc[i][0][r];
#pragma unroll
        for (int c = 1; c < 8; ++c)
#pragma unroll
          for (int r = 0; r < 4; ++r) tm[r] = fmaxf(tm[r], sc[i][c][r]);
#pragma unroll
        for (int msk = 1; msk <= 8; msk <<= 1)
#pragma unroll
          for (int r = 0; r < 4; ++r) tm[r] = fmaxf(tm[r], __shfl_xor(tm[r], msk, 64));
#pragma unroll
        for (int r = 0; r < 4; ++r) {
          float nm = fmaxf(mrun[i][r], tm[r]);
          float alpha = exp2f((mrun[i][r] - nm) * L2E);
          mrun[i][r] = nm;
          lrun[i][r] *= alpha;
#pragma unroll
          for (int jd = 0; jd < 8; ++jd) O[i][jd][r] *= alpha;
        }
        float rs[4] = {0.f, 0.f, 0.f, 0.f};
#pragma unroll
        for (int c = 0; c < 8; ++c)
#pragma unroll
          for (int r = 0; r < 4; ++r) {
            float pv = exp2f((sc[i][c][r] - mrun[i][r]) * L2E);
            sc[i][c][r] = pv;
            rs[r] += pv;
          }
#pragma unroll
        for (int msk = 1; msk <= 8; msk <<= 1)
#pragma unroll
          for (int r = 0; r < 4; ++r) rs[r] += __shfl_xor(rs[r], msk, 64);
#pragma unroll
        for (int r = 0; r < 4; ++r) lrun[i][r] += rs[r];
      }

      // ---- P·V in 32-key chunks ----
#pragma unroll
      for (int ks = 0; ks < 4; ++ks) {
#pragma unroll
        for (int i = 0; i < 2; ++i)
#pragma unroll
          for (int cc = 0; cc < 2; ++cc) {
            int c = ks * 2 + cc;
            int kg = cc * 2 + (lrow >> 3), off = lrow & 7;
#pragma unroll
            for (int r = 0; r < 4; ++r) {
              int q2 = i * 16 + quad * 4 + r;
              int slot = q2 * 4 + (kg ^ (q2 & 3) ^ ((q2 >> 2) & 3));
              Pw[slot * 8 + off] = f2bf(sc[i][c][r]);
            }
          }
        bf16x8 pa[2];
#pragma unroll
        for (int i = 0; i < 2; ++i) {
          int q2 = i * 16 + lrow;
          int slot = q2 * 4 + (quad ^ (q2 & 3) ^ ((q2 >> 2) & 3));
          pa[i] = *(const bf16x8*)&Pw[slot * 8];
        }
#pragma unroll
        for (int jd = 0; jd < 8; ++jd) {
          int d = jd * 16 + lrow;
          int slotv = d * 16 + ((ks * 4 + quad) ^ lrow);
          bf16x8 vb = *(const bf16x8*)&Vc[slotv * 8];
          O[0][jd] = __builtin_amdgcn_mfma_f32_16x16x32_bf16(pa[0], vb, O[0][jd], 0, 0, 0);
          O[1][jd] = __builtin_amdgcn_mfma_f32_16x16x32_bf16(pa[1], vb, O[1][jd], 0, 0, 0);
        }
      }
      __syncthreads();
    }

    // ---- epilogue ----
#pragma unroll
    for (int i = 0; i < 2; ++i)
#pragma unroll
      for (int r = 0; r < 4; ++r) {
        float inv = 1.f / lrun[i][r];
        int row = qt * 32 + i * 16 + quad * 4 + r;
#pragma unroll
        for (int jd = 0; jd < 8; ++jd)
          out[(size_t)row * DMODEL + h * HDIM + jd * 16 + lrow] = f2bf(O[i][jd][r] * inv);
      }
    __syncthreads();  // Ks/Vs safe for next phase's staging
  }
}

extern "C" void kernel_launch(void* const* d_in, const int* in_sizes, int n_in,
                              void* d_out, int out_size, void* d_ws, size_t ws_size,
                              hipStream_t stream) {
  const float* hs   = (const float*)d_in[0];
  const float* cosb = (const float*)d_in[1];
  const float* sinb = (const float*)d_in[2];
  const float* Wq   = (const float*)d_in[5];
  const float* Wk   = (const float*)d_in[6];
  const float* Wv   = (const float*)d_in[7];
  const float* Wo   = (const float*)d_in[8];
  const float* rmsw = (const float*)d_in[9];

  float* outp = (float*)d_out;
  float* kc = outp + (size_t)S_LEN * DMODEL;
  float* vc = kc + (size_t)MAXSEQ * NKV * HDIM;

  char* p = (char*)d_ws;
  short* h_bf  = (short*)p; p += (size_t)S_LEN * DMODEL * 2;
  short* WqkvT = (short*)p; p += (size_t)NQKV * DMODEL * 2;
  short* WoT   = (short*)p; p += (size_t)DMODEL * DMODEL * 2;
  float* QKV   = (float*)p; p += (size_t)S_LEN * NQKV * 4;
  short* q_bf  = (short*)p; p += (size_t)NHEAD * S_LEN * HDIM * 2;
  short* k_bf  = (short*)p; p += (size_t)NKV * S_LEN * HDIM * 2;
  short* vt_bf = (short*)p; p += (size_t)NKV * HDIM * S_LEN * 2;
  short* attn_bf = h_bf;  // alias: h consumed by gemm1 before attention writes

  const int ATTN_LDS = 139264;  // 64KB K dbuf + 64KB V dbuf + 8KB P
  hipFuncSetAttribute(reinterpret_cast<const void*>(attn_kernel),
                      hipFuncAttributeMaxDynamicSharedMemorySize, ATTN_LDS);

  rmsnorm_kernel<<<S_LEN, 256, 0, stream>>>(hs, rmsw, h_bf);
  cast_transpose<<<dim3(DMODEL / 32, DMODEL / 32), dim3(32, 8), 0, stream>>>(Wq, WqkvT, DMODEL, DMODEL);
  cast_transpose<<<dim3(1024 / 32, DMODEL / 32), dim3(32, 8), 0, stream>>>(Wk, WqkvT + (size_t)DMODEL * DMODEL, DMODEL, 1024);
  cast_transpose<<<dim3(1024 / 32, DMODEL / 32), dim3(32, 8), 0, stream>>>(Wv, WqkvT + (size_t)5120 * DMODEL, DMODEL, 1024);
  cast_transpose<<<dim3(DMODEL / 32, DMODEL / 32), dim3(32, 8), 0, stream>>>(Wo, WoT, DMODEL, DMODEL);
  gemm_bt<<<dim3(NQKV / 128, S_LEN / 128), 256, 0, stream>>>(h_bf, WqkvT, QKV, nullptr, S_LEN, NQKV, DMODEL);
  rope_kernel<<<S_LEN, 256, 0, stream>>>(QKV, cosb, sinb, q_bf, k_bf, kc);
  v_transpose<<<dim3(HDIM / 32, S_LEN / 32, NKV), dim3(32, 8), 0, stream>>>(QKV, vc, vt_bf);
  zero_tail<<<4096, 256, 0, stream>>>(kc, vc);
  attn_kernel<<<256, 256, ATTN_LDS, stream>>>(q_bf, k_bf, vt_bf, attn_bf);
  gemm_bt<<<dim3(DMODEL / 128, S_LEN / 128), 256, 0, stream>>>(attn_bf, WoT, outp, hs, S_LEN, DMODEL, DMODEL);
}